// Round 1
// baseline (1329.949 us; speedup 1.0000x reference)
//
#include <hip/hip_runtime.h>
#include <hip/hip_bf16.h>

typedef unsigned short u16;
typedef __bf16 bf16x8 __attribute__((ext_vector_type(8)));
typedef float f32x4 __attribute__((ext_vector_type(4)));
typedef unsigned short us8 __attribute__((ext_vector_type(8)));
typedef unsigned short us4 __attribute__((ext_vector_type(4)));

#define NB_RED 256

static __device__ __forceinline__ u16 f2bf(float f) {
    unsigned u = __builtin_bit_cast(unsigned, f);
    unsigned r = u + 0x7FFFu + ((u >> 16) & 1u);
    return (u16)(r >> 16);
}

// ---------------- min/max reduction (4 tensors) ----------------
__global__ void k_minmax_partial(const float* __restrict__ x, const float* __restrict__ h,
                                 const float* __restrict__ wi, const float* __restrict__ wh,
                                 float* __restrict__ partials) {
    int t = blockIdx.y;
    const float* p = (t == 0) ? x : (t == 1) ? h : (t == 2) ? wi : wh;
    int n4 = ((t < 2) ? (8192 * 1024) : (4096 * 1024)) >> 2;
    float mn = 3.4e38f, mx = -3.4e38f;
    const float4* p4 = (const float4*)p;
    for (int i = blockIdx.x * blockDim.x + threadIdx.x; i < n4; i += gridDim.x * blockDim.x) {
        float4 v = p4[i];
        mn = fminf(mn, fminf(fminf(v.x, v.y), fminf(v.z, v.w)));
        mx = fmaxf(mx, fmaxf(fmaxf(v.x, v.y), fmaxf(v.z, v.w)));
    }
    for (int d = 1; d < 64; d <<= 1) {
        mn = fminf(mn, __shfl_xor(mn, d));
        mx = fmaxf(mx, __shfl_xor(mx, d));
    }
    __shared__ float smn[4], smx[4];
    int wv = threadIdx.x >> 6;
    if ((threadIdx.x & 63) == 0) { smn[wv] = mn; smx[wv] = mx; }
    __syncthreads();
    if (threadIdx.x == 0) {
        mn = fminf(fminf(smn[0], smn[1]), fminf(smn[2], smn[3]));
        mx = fmaxf(fmaxf(smx[0], smx[1]), fmaxf(smx[2], smx[3]));
        partials[(t * NB_RED + blockIdx.x) * 2 + 0] = mn;
        partials[(t * NB_RED + blockIdx.x) * 2 + 1] = mx;
    }
}

__global__ void k_minmax_final(const float* __restrict__ partials, const int* __restrict__ nbits,
                               float* __restrict__ params) {
    int t = blockIdx.x;
    int tid = threadIdx.x;
    float mn = partials[(t * NB_RED + tid) * 2 + 0];
    float mx = partials[(t * NB_RED + tid) * 2 + 1];
    for (int d = 1; d < 64; d <<= 1) {
        mn = fminf(mn, __shfl_xor(mn, d));
        mx = fmaxf(mx, __shfl_xor(mx, d));
    }
    __shared__ float smn[4], smx[4];
    int wv = tid >> 6;
    if ((tid & 63) == 0) { smn[wv] = mn; smx[wv] = mx; }
    __syncthreads();
    if (tid == 0) {
        mn = fminf(fminf(smn[0], smn[1]), fminf(smn[2], smn[3]));
        mx = fmaxf(fmaxf(smx[0], smx[1]), fmaxf(smx[2], smx[3]));
        float qmax = (float)((1u << (*nbits)) - 1u);
        params[t * 2 + 0] = mn;
        params[t * 2 + 1] = (mx - mn) / qmax;
    }
}

// ---------------- quantize input|h -> Aq bf16 [8192][2048] ----------------
__global__ void k_quant_A(const float* __restrict__ x, const float* __restrict__ h,
                          const float* __restrict__ params, u16* __restrict__ Aq) {
    size_t i = (size_t)blockIdx.x * blockDim.x + threadIdx.x;
    const size_t nt4 = (size_t)8192 * 1024 / 4;
    int tsel = 0; const float* src = x;
    if (i >= nt4) { i -= nt4; tsel = 1; src = h; }
    float mn = params[tsel * 2 + 0], s = params[tsel * 2 + 1];
    float4 v = ((const float4*)src)[i];
    size_t e = i * 4;
    size_t b = e >> 10, k = e & 1023;
    us4 o;
    o.x = f2bf(rintf((v.x - mn) / s) * s + mn);
    o.y = f2bf(rintf((v.y - mn) / s) * s + mn);
    o.z = f2bf(rintf((v.z - mn) / s) * s + mn);
    o.w = f2bf(rintf((v.w - mn) / s) * s + mn);
    *(us4*)(Aq + b * 2048 + (size_t)tsel * 1024 + k) = o;
}

// ---- quantize W_in|W_h -> Wq bf16 [4096][2048], rows permuted to j*4+g ----
__global__ void k_quant_W(const float* __restrict__ wi, const float* __restrict__ wh,
                          const float* __restrict__ params, u16* __restrict__ Wq) {
    size_t i = (size_t)blockIdx.x * blockDim.x + threadIdx.x;
    const size_t nt4 = (size_t)4096 * 1024 / 4;
    int tsel = 0; const float* src = wi;
    if (i >= nt4) { i -= nt4; tsel = 1; src = wh; }
    float mn = params[(2 + tsel) * 2 + 0], s = params[(2 + tsel) * 2 + 1];
    float4 v = ((const float4*)src)[i];
    size_t e = i * 4;
    size_t row = e >> 10, k = e & 1023;
    size_t g = row >> 10, j = row & 1023;
    size_t prow = j * 4 + g;
    us4 o;
    o.x = f2bf(rintf((v.x - mn) / s) * s + mn);
    o.y = f2bf(rintf((v.y - mn) / s) * s + mn);
    o.z = f2bf(rintf((v.z - mn) / s) * s + mn);
    o.w = f2bf(rintf((v.w - mn) / s) * s + mn);
    *(us4*)(Wq + prow * 2048 + (size_t)tsel * 1024 + k) = o;
}

// ---------------- combined bias in permuted order ----------------
__global__ void k_bias(const float* __restrict__ b_in, const float* __restrict__ b_h,
                       float* __restrict__ bc) {
    int n = blockIdx.x * 256 + threadIdx.x;
    int j = n >> 2, g = n & 3;
    bc[n] = b_in[g * 1024 + j] + b_h[g * 1024 + j];
}

// ---------------- fused GEMM + LSTM pointwise ----------------
// C[m][n'] = sum_k Aq[m][k] * Wq[n'][k]; n' = j*4+g (permuted).
// 128x128 tile, BK=32, 4 waves (2x2), each wave 64x64 = 4x4 frags of 16x16x32.
__global__ __launch_bounds__(256) void k_gemm_lstm(
    const u16* __restrict__ Aq, const u16* __restrict__ Wq,
    const float* __restrict__ bc, const float* __restrict__ c_in,
    float* __restrict__ out) {
    __shared__ __align__(16) u16 As[128 * 32];
    __shared__ __align__(16) u16 Bs[128 * 32];
    __shared__ float eps[4][16 * 17];

    const int tid = threadIdx.x;
    const int wave = tid >> 6, lane = tid & 63;
    const int wr = wave >> 1, wc = wave & 1;
    const int la = lane & 15, hi = lane >> 4;
    const int bm = blockIdx.y * 128, bn = blockIdx.x * 128;

    const int srow = lane >> 2;        // row within a 16-row staging group
    const int ske = (lane & 3) * 8;    // k-element offset (8 bf16 = 16B)
    const size_t K = 2048;

    f32x4 acc[4][4];
#pragma unroll
    for (int m = 0; m < 4; m++)
#pragma unroll
        for (int n = 0; n < 4; n++) acc[m][n] = (f32x4)0.0f;

    for (int k0 = 0; k0 < 2048; k0 += 32) {
#pragma unroll
        for (int j2 = 0; j2 < 2; ++j2) {
            int rg = (j2 * 4 + wave) * 16 + srow;
            const u16* srcA = Aq + (size_t)(bm + rg) * K + k0 + ske;
            const u16* srcB = Wq + (size_t)(bn + rg) * K + k0 + ske;
            __builtin_amdgcn_global_load_lds(
                (const __attribute__((address_space(1))) void*)srcA,
                (__attribute__((address_space(3))) void*)&As[(j2 * 4 + wave) * 512], 16, 0, 0);
            __builtin_amdgcn_global_load_lds(
                (const __attribute__((address_space(1))) void*)srcB,
                (__attribute__((address_space(3))) void*)&Bs[(j2 * 4 + wave) * 512], 16, 0, 0);
        }
        __syncthreads();
        bf16x8 af[4], bfr[4];
#pragma unroll
        for (int m = 0; m < 4; m++)
            af[m] = __builtin_bit_cast(bf16x8, *(const us8*)&As[(wr * 64 + m * 16 + la) * 32 + hi * 8]);
#pragma unroll
        for (int n = 0; n < 4; n++)
            bfr[n] = __builtin_bit_cast(bf16x8, *(const us8*)&Bs[(wc * 64 + n * 16 + la) * 32 + hi * 8]);
#pragma unroll
        for (int m = 0; m < 4; m++)
#pragma unroll
            for (int n = 0; n < 4; n++)
                acc[m][n] = __builtin_amdgcn_mfma_f32_16x16x32_bf16(af[m], bfr[n], acc[m][n], 0, 0, 0);
        __syncthreads();
    }

    // Epilogue: per 16x16 frag, stage to per-wave LDS, compute LSTM, write h', c'.
#pragma unroll 1
    for (int m = 0; m < 4; m++) {
#pragma unroll 1
        for (int n = 0; n < 4; n++) {
            int colbase = bn + wc * 64 + n * 16;
            float bv = bc[colbase + la];
#pragma unroll
            for (int q = 0; q < 4; q++)
                eps[wave][(4 * hi + q) * 17 + la] = acc[m][n][q] + bv;
            __syncthreads();
            float g0 = eps[wave][la * 17 + hi * 4 + 0];
            float g1 = eps[wave][la * 17 + hi * 4 + 1];
            float g2 = eps[wave][la * 17 + hi * 4 + 2];
            float g3 = eps[wave][la * 17 + hi * 4 + 3];
            float iv = 1.0f / (1.0f + __expf(-g0));
            float fv = 1.0f / (1.0f + __expf(-g1));
            float gv = tanhf(g2);
            float ov = 1.0f / (1.0f + __expf(-g3));
            int rowg = bm + wr * 64 + m * 16 + la;
            int jg = (colbase >> 2) + hi;
            size_t off = (size_t)rowg * 1024 + jg;
            float cv = c_in[off];
            float cn = fv * cv + iv * gv;
            float hn = ov * tanhf(cn);
            out[off] = hn;
            out[(size_t)8192 * 1024 + off] = cn;
            __syncthreads();
        }
    }
}

extern "C" void kernel_launch(void* const* d_in, const int* in_sizes, int n_in,
                              void* d_out, int out_size, void* d_ws, size_t ws_size,
                              hipStream_t stream) {
    const float* x = (const float*)d_in[0];
    const float* h = (const float*)d_in[1];
    const float* c = (const float*)d_in[2];
    const float* wi = (const float*)d_in[3];
    const float* bi = (const float*)d_in[4];
    const float* wh = (const float*)d_in[5];
    const float* bh = (const float*)d_in[6];
    const int* nbits = (const int*)d_in[7];
    float* out = (float*)d_out;

    char* ws = (char*)d_ws;
    float* params = (float*)ws;                 // 8 f32
    float* partials = (float*)(ws + 64);        // 4*256*2 f32
    float* bc = (float*)(ws + 16384);           // 4096 f32
    u16* Aq = (u16*)(ws + 65536);               // 8192*2048 bf16 = 32MB
    u16* Wq = (u16*)(ws + 65536 + (size_t)32 * 1024 * 1024);  // 4096*2048 bf16 = 16MB

    k_minmax_partial<<<dim3(NB_RED, 4), 256, 0, stream>>>(x, h, wi, wh, partials);
    k_minmax_final<<<4, 256, 0, stream>>>(partials, nbits, params);
    k_quant_A<<<16384, 256, 0, stream>>>(x, h, params, Aq);
    k_quant_W<<<8192, 256, 0, stream>>>(wi, wh, params, Wq);
    k_bias<<<16, 256, 0, stream>>>(bi, bh, bc);
    k_gemm_lstm<<<dim3(32, 64), 256, 0, stream>>>(Aq, Wq, bc, c, out);
}

// Round 2
// 243.042 us; speedup vs baseline: 5.4721x; 5.4721x over previous
//
#include <hip/hip_runtime.h>
#include <hip/hip_bf16.h>

typedef unsigned short u16;
typedef __bf16 bf16x8 __attribute__((ext_vector_type(8)));
typedef float f32x4 __attribute__((ext_vector_type(4)));
typedef unsigned short us8 __attribute__((ext_vector_type(8)));
typedef unsigned short us4 __attribute__((ext_vector_type(4)));

#define NB_RED 256

static __device__ __forceinline__ u16 f2bf(float f) {
    unsigned u = __builtin_bit_cast(unsigned, f);
    unsigned r = u + 0x7FFFu + ((u >> 16) & 1u);
    return (u16)(r >> 16);
}

// ---------------- min/max reduction (4 tensors) ----------------
__global__ void k_minmax_partial(const float* __restrict__ x, const float* __restrict__ h,
                                 const float* __restrict__ wi, const float* __restrict__ wh,
                                 float* __restrict__ partials) {
    int t = blockIdx.y;
    const float* p = (t == 0) ? x : (t == 1) ? h : (t == 2) ? wi : wh;
    int n4 = ((t < 2) ? (8192 * 1024) : (4096 * 1024)) >> 2;
    float mn = 3.4e38f, mx = -3.4e38f;
    const float4* p4 = (const float4*)p;
    for (int i = blockIdx.x * blockDim.x + threadIdx.x; i < n4; i += gridDim.x * blockDim.x) {
        float4 v = p4[i];
        mn = fminf(mn, fminf(fminf(v.x, v.y), fminf(v.z, v.w)));
        mx = fmaxf(mx, fmaxf(fmaxf(v.x, v.y), fmaxf(v.z, v.w)));
    }
    for (int d = 1; d < 64; d <<= 1) {
        mn = fminf(mn, __shfl_xor(mn, d));
        mx = fmaxf(mx, __shfl_xor(mx, d));
    }
    __shared__ float smn[4], smx[4];
    int wv = threadIdx.x >> 6;
    if ((threadIdx.x & 63) == 0) { smn[wv] = mn; smx[wv] = mx; }
    __syncthreads();
    if (threadIdx.x == 0) {
        mn = fminf(fminf(smn[0], smn[1]), fminf(smn[2], smn[3]));
        mx = fmaxf(fmaxf(smx[0], smx[1]), fmaxf(smx[2], smx[3]));
        partials[(t * NB_RED + blockIdx.x) * 2 + 0] = mn;
        partials[(t * NB_RED + blockIdx.x) * 2 + 1] = mx;
    }
}

__global__ void k_minmax_final(const float* __restrict__ partials, const int* __restrict__ nbits,
                               float* __restrict__ params) {
    int t = blockIdx.x;
    int tid = threadIdx.x;
    float mn = partials[(t * NB_RED + tid) * 2 + 0];
    float mx = partials[(t * NB_RED + tid) * 2 + 1];
    for (int d = 1; d < 64; d <<= 1) {
        mn = fminf(mn, __shfl_xor(mn, d));
        mx = fmaxf(mx, __shfl_xor(mx, d));
    }
    __shared__ float smn[4], smx[4];
    int wv = tid >> 6;
    if ((tid & 63) == 0) { smn[wv] = mn; smx[wv] = mx; }
    __syncthreads();
    if (tid == 0) {
        mn = fminf(fminf(smn[0], smn[1]), fminf(smn[2], smn[3]));
        mx = fmaxf(fmaxf(smx[0], smx[1]), fmaxf(smx[2], smx[3]));
        float qmax = (float)((1u << (*nbits)) - 1u);
        params[t * 2 + 0] = mn;
        params[t * 2 + 1] = (mx - mn) / qmax;
    }
}

// ---------------- quantize input|h -> Aq bf16 [8192][2048] ----------------
__global__ void k_quant_A(const float* __restrict__ x, const float* __restrict__ h,
                          const float* __restrict__ params, u16* __restrict__ Aq) {
    size_t i = (size_t)blockIdx.x * blockDim.x + threadIdx.x;
    const size_t nt4 = (size_t)8192 * 1024 / 4;
    int tsel = 0; const float* src = x;
    if (i >= nt4) { i -= nt4; tsel = 1; src = h; }
    float mn = params[tsel * 2 + 0], s = params[tsel * 2 + 1];
    float4 v = ((const float4*)src)[i];
    size_t e = i * 4;
    size_t b = e >> 10, k = e & 1023;
    us4 o;
    o.x = f2bf(rintf((v.x - mn) / s) * s + mn);
    o.y = f2bf(rintf((v.y - mn) / s) * s + mn);
    o.z = f2bf(rintf((v.z - mn) / s) * s + mn);
    o.w = f2bf(rintf((v.w - mn) / s) * s + mn);
    *(us4*)(Aq + b * 2048 + (size_t)tsel * 1024 + k) = o;
}

// ---- quantize W_in|W_h -> Wq bf16 [4096][2048], rows permuted to j*4+g ----
__global__ void k_quant_W(const float* __restrict__ wi, const float* __restrict__ wh,
                          const float* __restrict__ params, u16* __restrict__ Wq) {
    size_t i = (size_t)blockIdx.x * blockDim.x + threadIdx.x;
    const size_t nt4 = (size_t)4096 * 1024 / 4;
    int tsel = 0; const float* src = wi;
    if (i >= nt4) { i -= nt4; tsel = 1; src = wh; }
    float mn = params[(2 + tsel) * 2 + 0], s = params[(2 + tsel) * 2 + 1];
    float4 v = ((const float4*)src)[i];
    size_t e = i * 4;
    size_t row = e >> 10, k = e & 1023;
    size_t g = row >> 10, j = row & 1023;
    size_t prow = j * 4 + g;
    us4 o;
    o.x = f2bf(rintf((v.x - mn) / s) * s + mn);
    o.y = f2bf(rintf((v.y - mn) / s) * s + mn);
    o.z = f2bf(rintf((v.z - mn) / s) * s + mn);
    o.w = f2bf(rintf((v.w - mn) / s) * s + mn);
    *(us4*)(Wq + prow * 2048 + (size_t)tsel * 1024 + k) = o;
}

// ---------------- combined bias in permuted order ----------------
__global__ void k_bias(const float* __restrict__ b_in, const float* __restrict__ b_h,
                       float* __restrict__ bc) {
    int n = blockIdx.x * 256 + threadIdx.x;
    int j = n >> 2, g = n & 3;
    bc[n] = b_in[g * 1024 + j] + b_h[g * 1024 + j];
}

// ---------------- fused GEMM + LSTM pointwise ----------------
// C[m][n'] = sum_k Aq[m][k] * Wq[n'][k]; n' = j*4+g (permuted).
// 128x128 tile, BK=32, 4 waves (2x2), each wave 64x64 = 4x4 frags of 16x16x32.
// NOTE: epilogue loops MUST be fully unrolled — runtime indexing of acc[][]
// sends the whole accumulator to scratch (rule #20; round-1 post-mortem:
// 7.8 GB of HBM writes = scratch spill traffic).
__global__ __launch_bounds__(256) void k_gemm_lstm(
    const u16* __restrict__ Aq, const u16* __restrict__ Wq,
    const float* __restrict__ bc, const float* __restrict__ c_in,
    float* __restrict__ out) {
    __shared__ __align__(16) u16 As[128 * 32];
    __shared__ __align__(16) u16 Bs[128 * 32];
    __shared__ float eps[4][16 * 17];

    const int tid = threadIdx.x;
    const int wave = tid >> 6, lane = tid & 63;
    const int wr = wave >> 1, wc = wave & 1;
    const int la = lane & 15, hi = lane >> 4;
    const int bm = blockIdx.y * 128, bn = blockIdx.x * 128;

    const int srow = lane >> 2;        // row within a 16-row staging group
    const int ske = (lane & 3) * 8;    // k-element offset (8 bf16 = 16B)
    const size_t K = 2048;

    f32x4 acc[4][4];
#pragma unroll
    for (int m = 0; m < 4; m++)
#pragma unroll
        for (int n = 0; n < 4; n++) acc[m][n] = (f32x4)0.0f;

    for (int k0 = 0; k0 < 2048; k0 += 32) {
#pragma unroll
        for (int j2 = 0; j2 < 2; ++j2) {
            int rg = (j2 * 4 + wave) * 16 + srow;
            const u16* srcA = Aq + (size_t)(bm + rg) * K + k0 + ske;
            const u16* srcB = Wq + (size_t)(bn + rg) * K + k0 + ske;
            __builtin_amdgcn_global_load_lds(
                (const __attribute__((address_space(1))) void*)srcA,
                (__attribute__((address_space(3))) void*)&As[(j2 * 4 + wave) * 512], 16, 0, 0);
            __builtin_amdgcn_global_load_lds(
                (const __attribute__((address_space(1))) void*)srcB,
                (__attribute__((address_space(3))) void*)&Bs[(j2 * 4 + wave) * 512], 16, 0, 0);
        }
        __syncthreads();
        bf16x8 af[4], bfr[4];
#pragma unroll
        for (int m = 0; m < 4; m++)
            af[m] = __builtin_bit_cast(bf16x8, *(const us8*)&As[(wr * 64 + m * 16 + la) * 32 + hi * 8]);
#pragma unroll
        for (int n = 0; n < 4; n++)
            bfr[n] = __builtin_bit_cast(bf16x8, *(const us8*)&Bs[(wc * 64 + n * 16 + la) * 32 + hi * 8]);
#pragma unroll
        for (int m = 0; m < 4; m++)
#pragma unroll
            for (int n = 0; n < 4; n++)
                acc[m][n] = __builtin_amdgcn_mfma_f32_16x16x32_bf16(af[m], bfr[n], acc[m][n], 0, 0, 0);
        __syncthreads();
    }

    // Epilogue: per 16x16 frag, stage to per-wave LDS, compute LSTM, write h', c'.
    // Fully unrolled: every acc index is compile-time constant.
#pragma unroll
    for (int m = 0; m < 4; m++) {
#pragma unroll
        for (int n = 0; n < 4; n++) {
            int colbase = bn + wc * 64 + n * 16;
            float bv = bc[colbase + la];
#pragma unroll
            for (int q = 0; q < 4; q++)
                eps[wave][(4 * hi + q) * 17 + la] = acc[m][n][q] + bv;
            __syncthreads();
            float g0 = eps[wave][la * 17 + hi * 4 + 0];
            float g1 = eps[wave][la * 17 + hi * 4 + 1];
            float g2 = eps[wave][la * 17 + hi * 4 + 2];
            float g3 = eps[wave][la * 17 + hi * 4 + 3];
            float iv = 1.0f / (1.0f + __expf(-g0));
            float fv = 1.0f / (1.0f + __expf(-g1));
            float gv = tanhf(g2);
            float ov = 1.0f / (1.0f + __expf(-g3));
            int rowg = bm + wr * 64 + m * 16 + la;
            int jg = (colbase >> 2) + hi;
            size_t off = (size_t)rowg * 1024 + jg;
            float cv = c_in[off];
            float cn = fv * cv + iv * gv;
            float hn = ov * tanhf(cn);
            out[off] = hn;
            out[(size_t)8192 * 1024 + off] = cn;
            __syncthreads();
        }
    }
}

extern "C" void kernel_launch(void* const* d_in, const int* in_sizes, int n_in,
                              void* d_out, int out_size, void* d_ws, size_t ws_size,
                              hipStream_t stream) {
    const float* x = (const float*)d_in[0];
    const float* h = (const float*)d_in[1];
    const float* c = (const float*)d_in[2];
    const float* wi = (const float*)d_in[3];
    const float* bi = (const float*)d_in[4];
    const float* wh = (const float*)d_in[5];
    const float* bh = (const float*)d_in[6];
    const int* nbits = (const int*)d_in[7];
    float* out = (float*)d_out;

    char* ws = (char*)d_ws;
    float* params = (float*)ws;                 // 8 f32
    float* partials = (float*)(ws + 64);        // 4*256*2 f32
    float* bc = (float*)(ws + 16384);           // 4096 f32
    u16* Aq = (u16*)(ws + 65536);               // 8192*2048 bf16 = 32MB
    u16* Wq = (u16*)(ws + 65536 + (size_t)32 * 1024 * 1024);  // 4096*2048 bf16 = 16MB

    k_minmax_partial<<<dim3(NB_RED, 4), 256, 0, stream>>>(x, h, wi, wh, partials);
    k_minmax_final<<<4, 256, 0, stream>>>(partials, nbits, params);
    k_quant_A<<<16384, 256, 0, stream>>>(x, h, params, Aq);
    k_quant_W<<<8192, 256, 0, stream>>>(wi, wh, params, Wq);
    k_bias<<<16, 256, 0, stream>>>(bi, bh, bc);
    k_gemm_lstm<<<dim3(32, 64), 256, 0, stream>>>(Aq, Wq, bc, c, out);
}

// Round 3
// 220.214 us; speedup vs baseline: 6.0393x; 1.1037x over previous
//
#include <hip/hip_runtime.h>
#include <hip/hip_bf16.h>

typedef unsigned short u16;
typedef __bf16 bf16x8 __attribute__((ext_vector_type(8)));
typedef float f32x4 __attribute__((ext_vector_type(4)));
typedef unsigned short us8 __attribute__((ext_vector_type(8)));
typedef unsigned short us4 __attribute__((ext_vector_type(4)));

#define NB_RED 256

static __device__ __forceinline__ u16 f2bf(float f) {
    unsigned u = __builtin_bit_cast(unsigned, f);
    unsigned r = u + 0x7FFFu + ((u >> 16) & 1u);
    return (u16)(r >> 16);
}

// ---------------- min/max reduction (4 tensors) ----------------
__global__ void k_minmax_partial(const float* __restrict__ x, const float* __restrict__ h,
                                 const float* __restrict__ wi, const float* __restrict__ wh,
                                 float* __restrict__ partials) {
    int t = blockIdx.y;
    const float* p = (t == 0) ? x : (t == 1) ? h : (t == 2) ? wi : wh;
    int n4 = ((t < 2) ? (8192 * 1024) : (4096 * 1024)) >> 2;
    float mn = 3.4e38f, mx = -3.4e38f;
    const float4* p4 = (const float4*)p;
    for (int i = blockIdx.x * blockDim.x + threadIdx.x; i < n4; i += gridDim.x * blockDim.x) {
        float4 v = p4[i];
        mn = fminf(mn, fminf(fminf(v.x, v.y), fminf(v.z, v.w)));
        mx = fmaxf(mx, fmaxf(fmaxf(v.x, v.y), fmaxf(v.z, v.w)));
    }
    for (int d = 1; d < 64; d <<= 1) {
        mn = fminf(mn, __shfl_xor(mn, d));
        mx = fmaxf(mx, __shfl_xor(mx, d));
    }
    __shared__ float smn[4], smx[4];
    int wv = threadIdx.x >> 6;
    if ((threadIdx.x & 63) == 0) { smn[wv] = mn; smx[wv] = mx; }
    __syncthreads();
    if (threadIdx.x == 0) {
        mn = fminf(fminf(smn[0], smn[1]), fminf(smn[2], smn[3]));
        mx = fmaxf(fmaxf(smx[0], smx[1]), fmaxf(smx[2], smx[3]));
        partials[(t * NB_RED + blockIdx.x) * 2 + 0] = mn;
        partials[(t * NB_RED + blockIdx.x) * 2 + 1] = mx;
    }
}

__global__ void k_minmax_final(const float* __restrict__ partials, const int* __restrict__ nbits,
                               float* __restrict__ params) {
    int t = blockIdx.x;
    int tid = threadIdx.x;
    float mn = partials[(t * NB_RED + tid) * 2 + 0];
    float mx = partials[(t * NB_RED + tid) * 2 + 1];
    for (int d = 1; d < 64; d <<= 1) {
        mn = fminf(mn, __shfl_xor(mn, d));
        mx = fmaxf(mx, __shfl_xor(mx, d));
    }
    __shared__ float smn[4], smx[4];
    int wv = tid >> 6;
    if ((tid & 63) == 0) { smn[wv] = mn; smx[wv] = mx; }
    __syncthreads();
    if (tid == 0) {
        mn = fminf(fminf(smn[0], smn[1]), fminf(smn[2], smn[3]));
        mx = fmaxf(fmaxf(smx[0], smx[1]), fmaxf(smx[2], smx[3]));
        float qmax = (float)((1u << (*nbits)) - 1u);
        params[t * 2 + 0] = mn;
        params[t * 2 + 1] = (mx - mn) / qmax;
    }
}

// ---------------- quantize input|h -> Aq bf16 [8192][2048] ----------------
__global__ void k_quant_A(const float* __restrict__ x, const float* __restrict__ h,
                          const float* __restrict__ params, u16* __restrict__ Aq) {
    size_t i = (size_t)blockIdx.x * blockDim.x + threadIdx.x;
    const size_t nt4 = (size_t)8192 * 1024 / 4;
    int tsel = 0; const float* src = x;
    if (i >= nt4) { i -= nt4; tsel = 1; src = h; }
    float mn = params[tsel * 2 + 0], s = params[tsel * 2 + 1];
    float4 v = ((const float4*)src)[i];
    size_t e = i * 4;
    size_t b = e >> 10, k = e & 1023;
    us4 o;
    o.x = f2bf(rintf((v.x - mn) / s) * s + mn);
    o.y = f2bf(rintf((v.y - mn) / s) * s + mn);
    o.z = f2bf(rintf((v.z - mn) / s) * s + mn);
    o.w = f2bf(rintf((v.w - mn) / s) * s + mn);
    *(us4*)(Aq + b * 2048 + (size_t)tsel * 1024 + k) = o;
}

// ---- quantize W_in|W_h -> Wq bf16 [4096][2048] ----
// Row permutation: original row = g*1024 + j  (gate g, unit j)
//   prow = (j>>4)*64 + g*16 + (j&15)
// so each 64-col wave sub-tile = 4 fragments = the 4 gates of 16 units,
// making the GEMM epilogue transpose-free.
__global__ void k_quant_W(const float* __restrict__ wi, const float* __restrict__ wh,
                          const float* __restrict__ params, u16* __restrict__ Wq) {
    size_t i = (size_t)blockIdx.x * blockDim.x + threadIdx.x;
    const size_t nt4 = (size_t)4096 * 1024 / 4;
    int tsel = 0; const float* src = wi;
    if (i >= nt4) { i -= nt4; tsel = 1; src = wh; }
    float mn = params[(2 + tsel) * 2 + 0], s = params[(2 + tsel) * 2 + 1];
    float4 v = ((const float4*)src)[i];
    size_t e = i * 4;
    size_t row = e >> 10, k = e & 1023;
    size_t g = row >> 10, j = row & 1023;
    size_t prow = (j >> 4) * 64 + g * 16 + (j & 15);
    us4 o;
    o.x = f2bf(rintf((v.x - mn) / s) * s + mn);
    o.y = f2bf(rintf((v.y - mn) / s) * s + mn);
    o.z = f2bf(rintf((v.z - mn) / s) * s + mn);
    o.w = f2bf(rintf((v.w - mn) / s) * s + mn);
    *(us4*)(Wq + prow * 2048 + (size_t)tsel * 1024 + k) = o;
}

// ---------------- combined bias in permuted order ----------------
__global__ void k_bias(const float* __restrict__ b_in, const float* __restrict__ b_h,
                       float* __restrict__ bc) {
    int n = blockIdx.x * 256 + threadIdx.x;   // n = permuted col index
    int j = (n >> 6) * 16 + (n & 15);
    int g = (n >> 4) & 3;
    bc[n] = b_in[g * 1024 + j] + b_h[g * 1024 + j];
}

// ---------------- fused GEMM + LSTM pointwise ----------------
// C[m][n'] = sum_k Aq[m][k] * Wq[n'][k]; n' permuted per k_quant_W.
// 128x128 tile, BK=32, 4 waves (2x2), each wave 64x64 = 4x4 frags of 16x16x32.
// LDS k-slot XOR swizzle (rule #21: linear LDS dest for global_load_lds,
// inverse-swizzled GLOBAL source + swizzled ds_read):
//   physical slot = logical slot ^ ((row>>1)&3)   (16B slots, 4 per 64B row)
// -> read bank groups (16*(R&1) + 4*(hi^f)) cover all 8 groups 2-way = free.
__global__ __launch_bounds__(256) void k_gemm_lstm(
    const u16* __restrict__ Aq, const u16* __restrict__ Wq,
    const float* __restrict__ bc, const float* __restrict__ c_in,
    float* __restrict__ out) {
    __shared__ __align__(16) u16 As[128 * 32];
    __shared__ __align__(16) u16 Bs[128 * 32];

    const int tid = threadIdx.x;
    const int wave = tid >> 6, lane = tid & 63;
    const int wr = wave >> 1, wc = wave & 1;
    const int la = lane & 15, hi = lane >> 4;
    const int bm = blockIdx.y * 128, bn = blockIdx.x * 128;

    const int srow = lane >> 2;                               // row within 16-row group
    const int ske = (((lane & 3) ^ ((srow >> 1) & 3)) * 8);   // pre-swizzled k-slot
    const int fR = (la >> 1) & 3;                             // read-side swizzle term
    const size_t K = 2048;

    f32x4 acc[4][4];
#pragma unroll
    for (int m = 0; m < 4; m++)
#pragma unroll
        for (int n = 0; n < 4; n++) acc[m][n] = (f32x4)0.0f;

    for (int k0 = 0; k0 < 2048; k0 += 32) {
#pragma unroll
        for (int j2 = 0; j2 < 2; ++j2) {
            int rg = (j2 * 4 + wave) * 16 + srow;
            const u16* srcA = Aq + (size_t)(bm + rg) * K + k0 + ske;
            const u16* srcB = Wq + (size_t)(bn + rg) * K + k0 + ske;
            __builtin_amdgcn_global_load_lds(
                (const __attribute__((address_space(1))) void*)srcA,
                (__attribute__((address_space(3))) void*)&As[(j2 * 4 + wave) * 512], 16, 0, 0);
            __builtin_amdgcn_global_load_lds(
                (const __attribute__((address_space(1))) void*)srcB,
                (__attribute__((address_space(3))) void*)&Bs[(j2 * 4 + wave) * 512], 16, 0, 0);
        }
        __syncthreads();
        bf16x8 af[4], bfr[4];
#pragma unroll
        for (int m = 0; m < 4; m++)
            af[m] = __builtin_bit_cast(bf16x8,
                *(const us8*)&As[(wr * 64 + m * 16 + la) * 32 + (hi ^ fR) * 8]);
#pragma unroll
        for (int n = 0; n < 4; n++)
            bfr[n] = __builtin_bit_cast(bf16x8,
                *(const us8*)&Bs[(wc * 64 + n * 16 + la) * 32 + (hi ^ fR) * 8]);
#pragma unroll
        for (int m = 0; m < 4; m++)
#pragma unroll
            for (int n = 0; n < 4; n++)
                acc[m][n] = __builtin_amdgcn_mfma_f32_16x16x32_bf16(af[m], bfr[n], acc[m][n], 0, 0, 0);
        __syncthreads();
    }

    // Epilogue: transpose-free. Fragment n of this wave = gate n of units
    // ub..ub+15 (col = la). C/D layout: col=lane&15, row=4*(lane>>4)+q.
    const int ub = ((bn + wc * 64) >> 6) * 16 + la;   // hidden-unit index
    float bv0 = bc[bn + wc * 64 + 0 * 16 + la];
    float bv1 = bc[bn + wc * 64 + 1 * 16 + la];
    float bv2 = bc[bn + wc * 64 + 2 * 16 + la];
    float bv3 = bc[bn + wc * 64 + 3 * 16 + la];
#pragma unroll
    for (int m = 0; m < 4; m++) {
#pragma unroll
        for (int q = 0; q < 4; q++) {
            int row = bm + wr * 64 + m * 16 + 4 * hi + q;
            float g0 = acc[m][0][q] + bv0;
            float g1 = acc[m][1][q] + bv1;
            float g2 = acc[m][2][q] + bv2;
            float g3 = acc[m][3][q] + bv3;
            float iv = 1.0f / (1.0f + __expf(-g0));
            float fv = 1.0f / (1.0f + __expf(-g1));
            float gv = tanhf(g2);
            float ov = 1.0f / (1.0f + __expf(-g3));
            size_t off = (size_t)row * 1024 + ub;
            float cv = c_in[off];
            float cn = fv * cv + iv * gv;
            float hn = ov * tanhf(cn);
            out[off] = hn;
            out[(size_t)8192 * 1024 + off] = cn;
        }
    }
}

extern "C" void kernel_launch(void* const* d_in, const int* in_sizes, int n_in,
                              void* d_out, int out_size, void* d_ws, size_t ws_size,
                              hipStream_t stream) {
    const float* x = (const float*)d_in[0];
    const float* h = (const float*)d_in[1];
    const float* c = (const float*)d_in[2];
    const float* wi = (const float*)d_in[3];
    const float* bi = (const float*)d_in[4];
    const float* wh = (const float*)d_in[5];
    const float* bh = (const float*)d_in[6];
    const int* nbits = (const int*)d_in[7];
    float* out = (float*)d_out;

    char* ws = (char*)d_ws;
    float* params = (float*)ws;                 // 8 f32
    float* partials = (float*)(ws + 64);        // 4*256*2 f32
    float* bc = (float*)(ws + 16384);           // 4096 f32
    u16* Aq = (u16*)(ws + 65536);               // 8192*2048 bf16 = 32MB
    u16* Wq = (u16*)(ws + 65536 + (size_t)32 * 1024 * 1024);  // 4096*2048 bf16 = 16MB

    k_minmax_partial<<<dim3(NB_RED, 4), 256, 0, stream>>>(x, h, wi, wh, partials);
    k_minmax_final<<<4, 256, 0, stream>>>(partials, nbits, params);
    k_quant_A<<<16384, 256, 0, stream>>>(x, h, params, Aq);
    k_quant_W<<<8192, 256, 0, stream>>>(wi, wh, params, Wq);
    k_bias<<<16, 256, 0, stream>>>(bi, bh, bc);
    k_gemm_lstm<<<dim3(32, 64), 256, 0, stream>>>(Aq, Wq, bc, c, out);
}

// Round 4
// 165.329 us; speedup vs baseline: 8.0443x; 1.3320x over previous
//
#include <hip/hip_runtime.h>
#include <hip/hip_bf16.h>

typedef unsigned short u16;
typedef int i32x4 __attribute__((ext_vector_type(4)));
typedef signed char s8;

#define NB_RED 256

// ---------------- min/max reduction (4 tensors) ----------------
__global__ void k_minmax_partial(const float* __restrict__ x, const float* __restrict__ h,
                                 const float* __restrict__ wi, const float* __restrict__ wh,
                                 float* __restrict__ partials) {
    int t = blockIdx.y;
    const float* p = (t == 0) ? x : (t == 1) ? h : (t == 2) ? wi : wh;
    int n4 = ((t < 2) ? (8192 * 1024) : (4096 * 1024)) >> 2;
    float mn = 3.4e38f, mx = -3.4e38f;
    const float4* p4 = (const float4*)p;
    for (int i = blockIdx.x * blockDim.x + threadIdx.x; i < n4; i += gridDim.x * blockDim.x) {
        float4 v = p4[i];
        mn = fminf(mn, fminf(fminf(v.x, v.y), fminf(v.z, v.w)));
        mx = fmaxf(mx, fmaxf(fmaxf(v.x, v.y), fmaxf(v.z, v.w)));
    }
    for (int d = 1; d < 64; d <<= 1) {
        mn = fminf(mn, __shfl_xor(mn, d));
        mx = fmaxf(mx, __shfl_xor(mx, d));
    }
    __shared__ float smn[4], smx[4];
    int wv = threadIdx.x >> 6;
    if ((threadIdx.x & 63) == 0) { smn[wv] = mn; smx[wv] = mx; }
    __syncthreads();
    if (threadIdx.x == 0) {
        mn = fminf(fminf(smn[0], smn[1]), fminf(smn[2], smn[3]));
        mx = fmaxf(fmaxf(smx[0], smx[1]), fmaxf(smx[2], smx[3]));
        partials[(t * NB_RED + blockIdx.x) * 2 + 0] = mn;
        partials[(t * NB_RED + blockIdx.x) * 2 + 1] = mx;
    }
}

__global__ void k_minmax_final(const float* __restrict__ partials, const int* __restrict__ nbits,
                               float* __restrict__ params) {
    int t = blockIdx.x;
    int tid = threadIdx.x;
    float mn = partials[(t * NB_RED + tid) * 2 + 0];
    float mx = partials[(t * NB_RED + tid) * 2 + 1];
    for (int d = 1; d < 64; d <<= 1) {
        mn = fminf(mn, __shfl_xor(mn, d));
        mx = fmaxf(mx, __shfl_xor(mx, d));
    }
    __shared__ float smn[4], smx[4];
    int wv = tid >> 6;
    if ((tid & 63) == 0) { smn[wv] = mn; smx[wv] = mx; }
    __syncthreads();
    if (tid == 0) {
        mn = fminf(fminf(smn[0], smn[1]), fminf(smn[2], smn[3]));
        mx = fmaxf(fmaxf(smx[0], smx[1]), fmaxf(smx[2], smx[3]));
        float qmax = (float)((1u << (*nbits)) - 1u);
        params[t * 2 + 0] = mn;
        params[t * 2 + 1] = (mx - mn) / qmax;
    }
}

static __device__ __forceinline__ int block_reduce_i(int v, int tid) {
    for (int d = 1; d < 64; d <<= 1) v += __shfl_xor(v, d);
    __shared__ int sred[4];
    if ((tid & 63) == 0) sred[tid >> 6] = v;
    __syncthreads();
    return sred[0] + sred[1] + sred[2] + sred[3];
}

// -------- quantize x|h -> A8 i8 levels-128, [8192][2048]; row level-sums -----
// One block = one source row (1024 elems = 256 threads x 4).
__global__ void k_quant_A(const float* __restrict__ x, const float* __restrict__ h,
                          const float* __restrict__ params, s8* __restrict__ A8,
                          float* __restrict__ Rax, float* __restrict__ Rah) {
    int b = blockIdx.x;            // 0..16383
    int tsel = b >> 13;            // 0: x, 1: h
    int row = b & 8191;
    const float* src = tsel ? h : x;
    float mn = params[tsel * 2 + 0], s = params[tsel * 2 + 1];
    int t = threadIdx.x;
    float4 v = ((const float4*)(src + (size_t)row * 1024))[t];
    int k0 = (int)fminf(255.f, fmaxf(0.f, rintf((v.x - mn) / s)));
    int k1 = (int)fminf(255.f, fmaxf(0.f, rintf((v.y - mn) / s)));
    int k2 = (int)fminf(255.f, fmaxf(0.f, rintf((v.z - mn) / s)));
    int k3 = (int)fminf(255.f, fmaxf(0.f, rintf((v.w - mn) / s)));
    unsigned p = ((unsigned)((k0 - 128) & 0xff)) | ((unsigned)((k1 - 128) & 0xff) << 8) |
                 ((unsigned)((k2 - 128) & 0xff) << 16) | ((unsigned)((k3 - 128) & 0xff) << 24);
    *(unsigned*)(A8 + (size_t)row * 2048 + tsel * 1024 + t * 4) = p;
    int sum = block_reduce_i(k0 + k1 + k2 + k3 - 512, t);
    if (t == 0) (tsel ? Rah : Rax)[row] = (float)sum;
}

// -------- quantize W_in|W_h -> W8 i8 levels-128, [4096][2048] permuted -------
// Row permutation: original row = g*1024 + j -> prow = (j>>4)*64 + g*16 + (j&15)
// so each 64-col wave sub-tile = the 4 gates of 16 units (transpose-free epilogue).
__global__ void k_quant_W(const float* __restrict__ wi, const float* __restrict__ wh,
                          const float* __restrict__ params, s8* __restrict__ W8,
                          float* __restrict__ Rbi, float* __restrict__ Rbh) {
    int b = blockIdx.x;            // 0..8191
    int tsel = b >> 12;            // 0: W_in, 1: W_h
    int row = b & 4095;            // original row g*1024+j
    const float* src = tsel ? wh : wi;
    float mn = params[(2 + tsel) * 2 + 0], s = params[(2 + tsel) * 2 + 1];
    int g = row >> 10, j = row & 1023;
    int prow = (j >> 4) * 64 + g * 16 + (j & 15);
    int t = threadIdx.x;
    float4 v = ((const float4*)(src + (size_t)row * 1024))[t];
    int k0 = (int)fminf(255.f, fmaxf(0.f, rintf((v.x - mn) / s)));
    int k1 = (int)fminf(255.f, fmaxf(0.f, rintf((v.y - mn) / s)));
    int k2 = (int)fminf(255.f, fmaxf(0.f, rintf((v.z - mn) / s)));
    int k3 = (int)fminf(255.f, fmaxf(0.f, rintf((v.w - mn) / s)));
    unsigned p = ((unsigned)((k0 - 128) & 0xff)) | ((unsigned)((k1 - 128) & 0xff) << 8) |
                 ((unsigned)((k2 - 128) & 0xff) << 16) | ((unsigned)((k3 - 128) & 0xff) << 24);
    *(unsigned*)(W8 + (size_t)prow * 2048 + tsel * 1024 + t * 4) = p;
    int sum = block_reduce_i(k0 + k1 + k2 + k3 - 512, t);
    if (t == 0) (tsel ? Rbh : Rbi)[prow] = (float)sum;
}

// ---------------- combined bias in permuted order ----------------
__global__ void k_bias(const float* __restrict__ b_in, const float* __restrict__ b_h,
                       float* __restrict__ bc) {
    int n = blockIdx.x * 256 + threadIdx.x;   // permuted col index
    int j = (n >> 6) * 16 + (n & 15);
    int g = (n >> 4) & 3;
    bc[n] = b_in[g * 1024 + j] + b_h[g * 1024 + j];
}

// ---------------- fused i8 GEMM + LSTM pointwise ----------------
// S[m][n'] = sum_k A8[m][k]*W8[n'][k], split into k<1024 (acc1: x*W_in) and
// k>=1024 (acc2: h*W_h) since scales differ. Gate reconstruction:
//   G = 1024*(za*zi + zh*zw) + cax*Rax[m] + cah*Rah[m] + cbx*Rbi[n'] +
//       cbh*Rbh[n'] + csx*S1 + csh*S2 + bias
// with z = mn + 128*s (value of level 128), c** per theory. Exact integers.
// 128x128 tile, BK=64 (i8), 4 waves, mfma_i32_16x16x64_i8.
// LDS swizzle identical geometry to validated bf16 version (64B rows, 4x16B
// slots, phys slot = logical ^ ((row>>1)&3); 0 bank conflicts measured).
__global__ __launch_bounds__(256, 2) void k_gemm_lstm(
    const s8* __restrict__ A8, const s8* __restrict__ W8,
    const float* __restrict__ params, const float* __restrict__ bc,
    const float* __restrict__ Rax, const float* __restrict__ Rah,
    const float* __restrict__ Rbi, const float* __restrict__ Rbh,
    const float* __restrict__ c_in, float* __restrict__ out) {
    __shared__ __align__(16) s8 As[128 * 64];
    __shared__ __align__(16) s8 Bs[128 * 64];

    const int tid = threadIdx.x;
    const int wave = tid >> 6, lane = tid & 63;
    const int wr = wave >> 1, wc = wave & 1;
    const int la = lane & 15, hi = lane >> 4;
    const int bm = blockIdx.y * 128, bn = blockIdx.x * 128;

    const int srow = lane >> 2;                                   // row in 16-row group
    const int skb = (((lane & 3) ^ ((srow >> 1) & 3)) * 16);      // pre-swizzled k-byte
    const int fR = (la >> 1) & 3;                                 // read-side swizzle

    i32x4 acc1[4][4], acc2[4][4];
#pragma unroll
    for (int m = 0; m < 4; m++)
#pragma unroll
        for (int n = 0; n < 4; n++) { acc1[m][n] = (i32x4)0; acc2[m][n] = (i32x4)0; }

#define KSTEP(ACC, K0)                                                                       \
    do {                                                                                     \
        _Pragma("unroll") for (int j2 = 0; j2 < 2; ++j2) {                                   \
            int rg = (j2 * 4 + wave) * 16 + srow;                                            \
            __builtin_amdgcn_global_load_lds(                                                \
                (const __attribute__((address_space(1))) void*)(A8 + (size_t)(bm + rg) * 2048 + (K0) + skb), \
                (__attribute__((address_space(3))) void*)&As[(j2 * 4 + wave) * 1024], 16, 0, 0); \
            __builtin_amdgcn_global_load_lds(                                                \
                (const __attribute__((address_space(1))) void*)(W8 + (size_t)(bn + rg) * 2048 + (K0) + skb), \
                (__attribute__((address_space(3))) void*)&Bs[(j2 * 4 + wave) * 1024], 16, 0, 0); \
        }                                                                                    \
        __syncthreads();                                                                     \
        i32x4 af[4], bfr[4];                                                                 \
        _Pragma("unroll") for (int m = 0; m < 4; m++)                                        \
            af[m] = *(const i32x4*)&As[(wr * 64 + m * 16 + la) * 64 + ((hi ^ fR) * 16)];     \
        _Pragma("unroll") for (int n = 0; n < 4; n++)                                        \
            bfr[n] = *(const i32x4*)&Bs[(wc * 64 + n * 16 + la) * 64 + ((hi ^ fR) * 16)];    \
        _Pragma("unroll") for (int m = 0; m < 4; m++)                                        \
            _Pragma("unroll") for (int n = 0; n < 4; n++)                                    \
                ACC[m][n] = __builtin_amdgcn_mfma_i32_16x16x64_i8(af[m], bfr[n], ACC[m][n], 0, 0, 0); \
        __syncthreads();                                                                     \
    } while (0)

    for (int ks = 0; ks < 16; ++ks) KSTEP(acc1, ks * 64);
    for (int ks = 16; ks < 32; ++ks) KSTEP(acc2, ks * 64);
#undef KSTEP

    // ---- epilogue: reconstruct gates from integer sums, LSTM pointwise ----
    float mna = params[0], sa = params[1], mnh = params[2], sh = params[3];
    float mni = params[4], si = params[5], mnw = params[6], sw = params[7];
    float za = mna + 128.0f * sa, zi = mni + 128.0f * si;
    float zh = mnh + 128.0f * sh, zw = mnw + 128.0f * sw;
    float C0 = 1024.0f * (za * zi + zh * zw);
    float cax = sa * zi, cah = sh * zw;
    float cbx = si * za, cbh = sw * zh;
    float csx = sa * si, csh = sh * sw;

    const int nb = bn + wc * 64;
    float colt[4];
#pragma unroll
    for (int g = 0; g < 4; ++g) {
        int np = nb + g * 16 + la;
        colt[g] = bc[np] + cbx * Rbi[np] + cbh * Rbh[np] + C0;
    }
    const int ub = (nb >> 6) * 16 + la;   // hidden-unit index

#pragma unroll
    for (int m = 0; m < 4; m++) {
#pragma unroll
        for (int q = 0; q < 4; q++) {
            int row = bm + wr * 64 + m * 16 + 4 * hi + q;
            float rterm = cax * Rax[row] + cah * Rah[row];
            float g0 = colt[0] + rterm + csx * (float)acc1[m][0][q] + csh * (float)acc2[m][0][q];
            float g1 = colt[1] + rterm + csx * (float)acc1[m][1][q] + csh * (float)acc2[m][1][q];
            float g2 = colt[2] + rterm + csx * (float)acc1[m][2][q] + csh * (float)acc2[m][2][q];
            float g3 = colt[3] + rterm + csx * (float)acc1[m][3][q] + csh * (float)acc2[m][3][q];
            float iv = 1.0f / (1.0f + __expf(-g0));
            float fv = 1.0f / (1.0f + __expf(-g1));
            float gv = tanhf(g2);
            float ov = 1.0f / (1.0f + __expf(-g3));
            size_t off = (size_t)row * 1024 + ub;
            float cv = c_in[off];
            float cn = fv * cv + iv * gv;
            float hn = ov * tanhf(cn);
            out[off] = hn;
            out[(size_t)8192 * 1024 + off] = cn;
        }
    }
}

extern "C" void kernel_launch(void* const* d_in, const int* in_sizes, int n_in,
                              void* d_out, int out_size, void* d_ws, size_t ws_size,
                              hipStream_t stream) {
    const float* x = (const float*)d_in[0];
    const float* h = (const float*)d_in[1];
    const float* c = (const float*)d_in[2];
    const float* wi = (const float*)d_in[3];
    const float* bi = (const float*)d_in[4];
    const float* wh = (const float*)d_in[5];
    const float* bh = (const float*)d_in[6];
    const int* nbits = (const int*)d_in[7];
    float* out = (float*)d_out;

    char* ws = (char*)d_ws;
    float* params   = (float*)ws;                   // 8 f32
    float* partials = (float*)(ws + 64);            // 4*256*2 f32
    float* bc  = (float*)(ws + 16384);              // 4096 f32
    float* Rax = (float*)(ws + 32768);              // 8192 f32
    float* Rah = (float*)(ws + 65536);              // 8192 f32
    float* Rbi = (float*)(ws + 98304);              // 4096 f32
    float* Rbh = (float*)(ws + 114688);             // 4096 f32
    s8* A8 = (s8*)(ws + 131072);                    // 8192*2048 i8 = 16MB
    s8* W8 = (s8*)(ws + 131072 + (size_t)16 * 1024 * 1024);  // 4096*2048 i8 = 8MB

    k_minmax_partial<<<dim3(NB_RED, 4), 256, 0, stream>>>(x, h, wi, wh, partials);
    k_minmax_final<<<4, 256, 0, stream>>>(partials, nbits, params);
    k_quant_A<<<16384, 256, 0, stream>>>(x, h, params, A8, Rax, Rah);
    k_quant_W<<<8192, 256, 0, stream>>>(wi, wh, params, W8, Rbi, Rbh);
    k_bias<<<16, 256, 0, stream>>>(bi, bh, bc);
    k_gemm_lstm<<<dim3(32, 64), 256, 0, stream>>>(A8, W8, params, bc, Rax, Rah, Rbi, Rbh, c, out);
}